// Round 10
// baseline (322.981 us; speedup 1.0000x reference)
//
#include <hip/hip_runtime.h>

namespace {
constexpr int B_ = 64, S_ = 200, DV_ = 128, NC2_ = 4096;
constexpr int FCH = 8, NFCH = 25;    // fill: 25 chunks x 8 rows
constexpr int ACH = 50, NACH = 4;    // alpha: 4 chunks x 50 rows
constexpr int NGB = 4;               // GRU blocks, 16 batches each
}

typedef float f4v __attribute__((ext_vector_type(4)));
typedef float float4v __attribute__((ext_vector_type(4)));
typedef _Float16 half8 __attribute__((ext_vector_type(8)));

// LDS-only barrier: no vmcnt drain.
__device__ __forceinline__ void lds_sync() {
  asm volatile("s_waitcnt lgkmcnt(0)\n\ts_barrier" ::: "memory");
}

// Full-wave (64) sum via DPP; result broadcast to all lanes via readlane 63.
__device__ __forceinline__ float wave_sum_bcast(float x) {
  float a = x;
  int s = __builtin_bit_cast(int, a);
  s = __builtin_amdgcn_update_dpp(0, s, 0x111, 0xf, 0xf, true);  // row_shr:1
  a += __builtin_bit_cast(float, s);
  s = __builtin_bit_cast(int, a);
  s = __builtin_amdgcn_update_dpp(0, s, 0x112, 0xf, 0xf, true);  // row_shr:2
  a += __builtin_bit_cast(float, s);
  s = __builtin_bit_cast(int, a);
  s = __builtin_amdgcn_update_dpp(0, s, 0x114, 0xf, 0xf, true);  // row_shr:4
  a += __builtin_bit_cast(float, s);
  s = __builtin_bit_cast(int, a);
  s = __builtin_amdgcn_update_dpp(0, s, 0x118, 0xf, 0xf, true);  // row_shr:8
  a += __builtin_bit_cast(float, s);
  s = __builtin_bit_cast(int, a);
  s = __builtin_amdgcn_update_dpp(0, s, 0x142, 0xf, 0xf, true);  // row_bcast:15
  a += __builtin_bit_cast(float, s);
  s = __builtin_bit_cast(int, a);
  s = __builtin_amdgcn_update_dpp(0, s, 0x143, 0xf, 0xf, true);  // row_bcast:31
  a += __builtin_bit_cast(float, s);
  s = __builtin_bit_cast(int, a);
  return __builtin_bit_cast(float, __builtin_amdgcn_readlane(s, 63));
}

// ---------------------------------------------------------------------------
// K1: blocks [0,4):   GRU, 16 batches per block via MFMA 16x16x32_f16.
//                     8 waves; wave w owns output dims [16w,16w+16) of all 3
//                     gates. W_hh fragments in registers; H double-buffered
//                     in swizzled LDS; activation fully in-register.
//     blocks [4,68):  C2 value scan per batch, single wave, DPP reduce.
// ---------------------------------------------------------------------------
__global__ __launch_bounds__(512, 1) void k1_gru_scan(
    const int* __restrict__ c2_seq, const int* __restrict__ d_seq,
    const int* __restrict__ r_seq, const float* __restrict__ D_emb,
    const float* __restrict__ v_d, const float* __restrict__ v_c2,
    const float* __restrict__ R_emb,
    const float* __restrict__ W_ih, const float* __restrict__ W_hh,
    const float* __restrict__ b_ih, const float* __restrict__ b_hh,
    const float* __restrict__ W3, const float* __restrict__ b3,
    const float* __restrict__ W4, const float* __restrict__ b4,
    float* __restrict__ out_h, float* __restrict__ vals_ws)
{
  __shared__ __align__(16) char smem[28032];
  const int tid = threadIdx.x;

  if (blockIdx.x < NGB) {
    // ------------------ GRU for batches [bs0, bs0+16) ------------------
    const int bs0 = blockIdx.x * 16;
    _Float16* hist = reinterpret_cast<_Float16*>(smem);      // 2*16*128 f16
    float* gam = reinterpret_cast<float*>(smem + 8192);      // [200][16]
    uint* rmsk = reinterpret_cast<uint*>(smem + 20992);      // [200]
    float* u_l = reinterpret_cast<float*>(smem + 21808);     // [384]
    float* p0_l = u_l + 384;
    float* p1_l = p0_l + 384;
    float* bh_l = p1_l + 384;

    // ---- stage gamma / r-mask ----
    for (int i = tid; i < S_ * 16; i += 512) {
      const int t = i >> 4, b = i & 15;
      gam[i] = D_emb[d_seq[(size_t)(bs0 + b) * S_ + t]];
    }
    if (tid < S_) {
      uint m = 0;
      for (int b = 0; b < 16; ++b)
        m |= (uint)(r_seq[(size_t)(bs0 + b) * S_ + tid] & 1) << b;
      rmsk[tid] = m;
    }
    // ---- zero both hist buffers ----
    for (int i = tid; i < 2048; i += 512)
      reinterpret_cast<uint*>(hist)[i] = 0u;

    // ---- collapsed input projections per gate row ----
    if (tid < 384) {
      const int row = tid;
      const float4* wi =
          reinterpret_cast<const float4*>(W_ih + (size_t)row * 2 * DV_);
      const float4* vd4 = reinterpret_cast<const float4*>(v_d);
      const float4* re4 = reinterpret_cast<const float4*>(R_emb);
      float uu = 0.f, pp0 = 0.f, pp1 = 0.f;
#pragma unroll 8
      for (int k = 0; k < DV_ / 4; ++k) {
        float4 a = wi[k], vv = vd4[k];
        uu += a.x * vv.x + a.y * vv.y + a.z * vv.z + a.w * vv.w;
        float4 c = wi[DV_ / 4 + k];
        float4 r0 = re4[k], r1 = re4[DV_ / 4 + k];
        pp0 += c.x * r0.x + c.y * r0.y + c.z * r0.z + c.w * r0.w;
        pp1 += c.x * r1.x + c.y * r1.y + c.z * r1.z + c.w * r1.w;
      }
      const float bi = b_ih[row];
      u_l[row] = uu; p0_l[row] = pp0 + bi; p1_l[row] = pp1 + bi;
      bh_l[row] = b_hh[row];
    }

    // ---- W_hh^T B-fragments in registers: bf[gate][ktile] ----
    const int w = tid >> 6, l = tid & 63;
    const int col = l & 15, kg = l >> 4;
    half8 bf[3][4];
#pragma unroll
    for (int g = 0; g < 3; ++g) {
      const float* wr = W_hh + (size_t)(16 * w + g * 128 + col) * DV_;
#pragma unroll
      for (int kt = 0; kt < 4; ++kt) {
        const int k0 = kt * 32 + kg * 8;
        half8 hb;
#pragma unroll
        for (int j = 0; j < 8; ++j) hb[j] = (_Float16)wr[k0 + j];
        bf[g][kt] = hb;
      }
    }
    __syncthreads();

    // ---- per-lane constants ----
    const int d = 16 * w + col;
    float u3[3], p03[3], p13[3], bh3[3];
#pragma unroll
    for (int g = 0; g < 3; ++g) {
      u3[g] = u_l[g * 128 + d];
      p03[g] = p0_l[g * 128 + d];
      p13[g] = p1_l[g * 128 + d];
      bh3[g] = bh_l[g * 128 + d];
    }
    float hprev[4] = {0.f, 0.f, 0.f, 0.f};

    for (int t = 0; t < S_; ++t) {
      const int cur = t & 1;
      // A-fragments from swizzled LDS (row = l&15 -> batch, k contiguous 8)
      half8 af[4];
#pragma unroll
      for (int kt = 0; kt < 4; ++kt) {
        const int row = col;  // A row index = l&15
        const int c0 = (kt * 32 + kg * 8) ^ ((row & 7) << 3);
        af[kt] = *reinterpret_cast<const half8*>(&hist[cur * 2048 + row * 128 + c0]);
      }
      float4v acc0 = {0.f, 0.f, 0.f, 0.f}, acc1 = acc0, acc2 = acc0;
#pragma unroll
      for (int kt = 0; kt < 4; ++kt) {
        acc0 = __builtin_amdgcn_mfma_f32_16x16x32_f16(af[kt], bf[0][kt], acc0, 0, 0, 0);
        acc1 = __builtin_amdgcn_mfma_f32_16x16x32_f16(af[kt], bf[1][kt], acc1, 0, 0, 0);
        acc2 = __builtin_amdgcn_mfma_f32_16x16x32_f16(af[kt], bf[2][kt], acc2, 0, 0, 0);
      }
      const uint rm = rmsk[t];
#pragma unroll
      for (int j = 0; j < 4; ++j) {
        const int b = kg * 4 + j;             // C row = batch
        const float gv = gam[t * 16 + b];
        const bool rb = (rm >> b) & 1u;
        const float xr = gv * u3[0] + (rb ? p13[0] : p03[0]);
        const float xz = gv * u3[1] + (rb ? p13[1] : p03[1]);
        const float xn = gv * u3[2] + (rb ? p13[2] : p03[2]);
        const float r = 1.f / (1.f + __expf(-(xr + acc0[j] + bh3[0])));
        const float z = 1.f / (1.f + __expf(-(xz + acc1[j] + bh3[1])));
        const float nx = xn + r * (acc2[j] + bh3[2]);
        const float e2 = __expf(2.f * nx);
        const float n = (e2 - 1.f) / (e2 + 1.f);
        const float hnew = (1.f - z) * n + z * hprev[j];
        hprev[j] = hnew;
        out_h[((size_t)(bs0 + b) * S_ + t) * DV_ + d] = hnew;
        hist[(cur ^ 1) * 2048 + b * 128 + (d ^ ((b & 7) << 3))] = (_Float16)hnew;
      }
      lds_sync();
    }
  } else {
    // ------------------ C2 value scan, single wave, DPP reduce ----------
    const int b = blockIdx.x - NGB;
    float* C2s = reinterpret_cast<float*>(smem);             // 4096
    float* gl = C2s + NC2_;
    int* rl = reinterpret_cast<int*>(gl + S_);
    int* jl = rl + S_;
    for (int i = tid; i < NC2_; i += 512) C2s[i] = 0.f;
    for (int i = tid; i < S_; i += 512) {
      gl[i] = D_emb[d_seq[b * S_ + i]];
      rl[i] = r_seq[b * S_ + i];
      jl[i] = c2_seq[b * S_ + i];
    }
    __syncthreads();
    if (tid >= 64) return;
    const int lane = tid;
    float a3L = 0, u3L = 0, q0L = 0, q1L = 0;
    float a3H = 0, u3H = 0, q0H = 0, q1H = 0;
    {
      const float4* vc4 = reinterpret_cast<const float4*>(v_c2);
      const float4* vd4 = reinterpret_cast<const float4*>(v_d);
      const float4* re4 = reinterpret_cast<const float4*>(R_emb);
      const float4* wL = reinterpret_cast<const float4*>(W3 + (size_t)lane * 3 * DV_);
      const float4* wH = reinterpret_cast<const float4*>(W3 + (size_t)(lane + 64) * 3 * DV_);
#pragma unroll 8
      for (int k = 0; k < DV_ / 4; ++k) {
        float4 cc = vc4[k], dd = vd4[k];
        float4 r0 = re4[k], r1 = re4[DV_ / 4 + k];
        float4 aL = wL[k], aH = wH[k];
        a3L += aL.x * cc.x + aL.y * cc.y + aL.z * cc.z + aL.w * cc.w;
        a3H += aH.x * cc.x + aH.y * cc.y + aH.z * cc.z + aH.w * cc.w;
        float4 bL = wL[DV_ / 4 + k], bH = wH[DV_ / 4 + k];
        u3L += bL.x * dd.x + bL.y * dd.y + bL.z * dd.z + bL.w * dd.w;
        u3H += bH.x * dd.x + bH.y * dd.y + bH.z * dd.z + bH.w * dd.w;
        float4 cL = wL[2 * (DV_ / 4) + k], cH = wH[2 * (DV_ / 4) + k];
        q0L += cL.x * r0.x + cL.y * r0.y + cL.z * r0.z + cL.w * r0.w;
        q1L += cL.x * r1.x + cL.y * r1.y + cL.z * r1.z + cL.w * r1.w;
        q0H += cH.x * r0.x + cH.y * r0.y + cH.z * r0.z + cH.w * r0.w;
        q1H += cH.x * r1.x + cH.y * r1.y + cH.z * r1.z + cH.w * r1.w;
      }
      float bbL = b3[lane], bbH = b3[lane + 64];
      q0L += bbL; q1L += bbL; q0H += bbH; q1H += bbH;
    }
    const float w4L = W4[lane], w4H = W4[lane + 64];
    const float b4v = b4[0];

    int jc = jl[0];
    float gv = gl[0];
    int rv = rl[0];
    float pf = 0.f;
    float lastv = 0.f;
    int lastj = -1;
    for (int t = 0; t < S_; ++t) {
      const int tn = (t + 1 < S_) ? t + 1 : 0;
      const int jn = jl[tn];
      const float gvn = gl[tn];
      const int rvn = rl[tn];
      const float pfn = C2s[jn];   // prefetch; patched via lastj/lastv
      const float beta = (jc == lastj) ? lastv : pf;
      float hL = beta * a3L + gv * u3L + (rv ? q1L : q0L);
      float hH = beta * a3H + gv * u3H + (rv ? q1H : q0H);
      const float part = fmaxf(hL, 0.f) * w4L + fmaxf(hH, 0.f) * w4H;
      const float val = wave_sum_bcast(part) + b4v;
      if (lane == 0) {
        C2s[jc] = val;
        vals_ws[b * S_ + t] = val;
      }
      lastj = jc; lastv = val;
      jc = jn; gv = gvn; rv = rvn; pf = pfn;
    }
  }
}

// ---------------------------------------------------------------------------
// K2: blocks [0,256):    alpha MLP, (b, 50-row chunk)
//     blocks [256,1856): C2_seq fill, (b, 8-row chunk), barrier-free rows
// ---------------------------------------------------------------------------
__global__ __launch_bounds__(256) void k2_alpha_fill(
    const int* __restrict__ c2_seq,
    const float* __restrict__ W1, const float* __restrict__ b1,
    const float* __restrict__ W2, const float* __restrict__ b2,
    const float* __restrict__ vals_ws, const float* __restrict__ h_seq,
    float* __restrict__ out_alpha, float* __restrict__ out_c2)
{
  const int tid = threadIdx.x;
  if (blockIdx.x < NACH * B_) {
    // ------------------ alpha ------------------
    const int b = blockIdx.x >> 2, c = blockIdx.x & 3;
    const int sbeg = c * ACH, send = sbeg + ACH;
    __shared__ float4 hb4[2][DV_ / 4];
    __shared__ float red[4];
    const int grp = tid >> 7, d = tid & 127;
    float w1r[DV_];
    {
      const float4* wr = reinterpret_cast<const float4*>(W1 + (size_t)d * DV_);
#pragma unroll
      for (int k = 0; k < DV_ / 4; ++k) {
        float4 t4 = wr[k];
        w1r[4 * k] = t4.x; w1r[4 * k + 1] = t4.y;
        w1r[4 * k + 2] = t4.z; w1r[4 * k + 3] = t4.w;
      }
    }
    const float b1v = b1[d], w2v = W2[d], b2v = b2[0];
    float* hb = reinterpret_cast<float*>(hb4[grp]);
    for (int s = sbeg; s < send; s += 2) {
      const int ss = s + grp;
      hb[d] = h_seq[((size_t)(b * S_ + ss)) * DV_ + d];
      __syncthreads();
      float y0 = b1v, y1 = 0, y2 = 0, y3 = 0;
#pragma unroll
      for (int k = 0; k < DV_ / 4; ++k) {
        float4 hv = hb4[grp][k];
        y0 += w1r[4 * k + 0] * hv.x; y1 += w1r[4 * k + 1] * hv.y;
        y2 += w1r[4 * k + 2] * hv.z; y3 += w1r[4 * k + 3] * hv.w;
      }
      float part = w2v * fmaxf((y0 + y1) + (y2 + y3), 0.f);
#pragma unroll
      for (int off = 1; off < 64; off <<= 1) part += __shfl_xor(part, off);
      if ((tid & 63) == 0) red[tid >> 6] = part;
      __syncthreads();
      if (d == 0) out_alpha[b * S_ + ss] = red[2 * grp] + red[2 * grp + 1] + b2v;
      __syncthreads();
    }
  } else {
    // ------------------ C2_seq fill ------------------
    const int blk = blockIdx.x - NACH * B_;
    const int b = blk / NFCH, c = blk % NFCH;
    const int s0 = c * FCH;
    __shared__ float vls[S_];
    __shared__ int jl[S_];
    for (int i = tid; i < S_; i += 256) {
      vls[i] = vals_ws[b * S_ + i];
      jl[i] = c2_seq[b * S_ + i];
    }
    __syncthreads();
    // thread owns 16 columns: float4 indices f = tid + jj*256
    f4v v0 = {0.f, 0.f, 0.f, 0.f}, v1 = v0, v2 = v0, v3 = v0;

#define APPLY_EVT(T)                                                          \
    {                                                                         \
      const int j_ = jl[(T)];                                                 \
      const int f_ = j_ >> 2;                                                 \
      if ((f_ & 255) == tid) {                                                \
        const float vv_ = vls[(T)];                                           \
        const int rr_ = f_ >> 8, q_ = j_ & 3;                                 \
        if (rr_ == 0) {                                                       \
          if (q_ == 0) v0.x = vv_; else if (q_ == 1) v0.y = vv_;              \
          else if (q_ == 2) v0.z = vv_; else v0.w = vv_;                      \
        } else if (rr_ == 1) {                                                \
          if (q_ == 0) v1.x = vv_; else if (q_ == 1) v1.y = vv_;              \
          else if (q_ == 2) v1.z = vv_; else v1.w = vv_;                      \
        } else if (rr_ == 2) {                                                \
          if (q_ == 0) v2.x = vv_; else if (q_ == 1) v2.y = vv_;              \
          else if (q_ == 2) v2.z = vv_; else v2.w = vv_;                      \
        } else {                                                              \
          if (q_ == 0) v3.x = vv_; else if (q_ == 1) v3.y = vv_;              \
          else if (q_ == 2) v3.z = vv_; else v3.w = vv_;                      \
        }                                                                     \
      }                                                                       \
    }

    for (int t = 0; t < s0; ++t) APPLY_EVT(t);

    f4v* dst4 = reinterpret_cast<f4v*>(out_c2 + (size_t)b * S_ * NC2_);
    for (int s = s0; s < s0 + FCH; ++s) {
      APPLY_EVT(s);
      f4v* drow = dst4 + (size_t)s * (NC2_ / 4);
      __builtin_nontemporal_store(v0, drow + tid);
      __builtin_nontemporal_store(v1, drow + tid + 256);
      __builtin_nontemporal_store(v2, drow + tid + 512);
      __builtin_nontemporal_store(v3, drow + tid + 768);
    }
#undef APPLY_EVT
  }
}

extern "C" void kernel_launch(void* const* d_in, const int* in_sizes, int n_in,
                              void* d_out, int out_size, void* d_ws, size_t ws_size,
                              hipStream_t stream) {
  const int* c2_seq = (const int*)d_in[1];
  const int* d_seq = (const int*)d_in[3];
  const int* r_seq = (const int*)d_in[4];
  const float* D_emb = (const float*)d_in[5];
  const float* v_d = (const float*)d_in[6];
  const float* v_c2 = (const float*)d_in[7];
  const float* R_emb = (const float*)d_in[8];
  const float* W_ih = (const float*)d_in[9];
  const float* W_hh = (const float*)d_in[10];
  const float* b_ih = (const float*)d_in[11];
  const float* b_hh = (const float*)d_in[12];
  const float* W1 = (const float*)d_in[13];
  const float* b1 = (const float*)d_in[14];
  const float* W2 = (const float*)d_in[15];
  const float* b2 = (const float*)d_in[16];
  const float* W3 = (const float*)d_in[17];
  const float* b3 = (const float*)d_in[18];
  const float* W4 = (const float*)d_in[19];
  const float* b4 = (const float*)d_in[20];

  float* out = (float*)d_out;
  float* out_alpha = out;                                  // [B,S]
  float* out_h = out + B_ * S_;                            // [B,S,DV]
  float* out_c2 = out + B_ * S_ + (size_t)B_ * S_ * DV_;   // [B,S,NC2]
  float* vals_ws = (float*)d_ws;                           // [B*S] floats

  k1_gru_scan<<<dim3(NGB + B_), dim3(512), 0, stream>>>(
      c2_seq, d_seq, r_seq, D_emb, v_d, v_c2, R_emb, W_ih, W_hh, b_ih, b_hh,
      W3, b3, W4, b4, out_h, vals_ws);
  k2_alpha_fill<<<dim3(NACH * B_ + B_ * NFCH), dim3(256), 0, stream>>>(
      c2_seq, W1, b1, W2, b2, vals_ws, out_h, out_alpha, out_c2);
}

// Round 11
// 183.607 us; speedup vs baseline: 1.7591x; 1.7591x over previous
//
#include <hip/hip_runtime.h>

namespace {
constexpr int B_ = 64, S_ = 200, DV_ = 128, NC2_ = 4096;
constexpr int FCH = 8, NFCH = 25;    // fill: 25 chunks x 8 rows
constexpr int ACH = 50, NACH = 4;    // alpha: 4 chunks x 50 rows
}

typedef float f4v __attribute__((ext_vector_type(4)));
typedef _Float16 h2v __attribute__((ext_vector_type(2)));

#if defined(__has_builtin)
#if __has_builtin(__builtin_amdgcn_fdot2)
#define HAVE_FDOT2 1
#endif
#endif

__device__ __forceinline__ float dot2acc(h2v a, h2v b, float c) {
#ifdef HAVE_FDOT2
  return __builtin_amdgcn_fdot2(a, b, c, false);
#else
  return c + (float)a.x * (float)b.x + (float)a.y * (float)b.y;
#endif
}

// LDS-only barrier: no vmcnt drain (no vmem ordering needed in the GRU loop).
__device__ __forceinline__ void lds_sync() {
  asm volatile("s_waitcnt lgkmcnt(0)\n\ts_barrier" ::: "memory");
}

// lane-pair (l ^ 1) sum via DPP quad_perm [1,0,3,2] -- VALU speed, no LDS.
__device__ __forceinline__ float pair_sum(float x) {
  int s = __builtin_amdgcn_update_dpp(
      0, __builtin_bit_cast(int, x), 0xB1, 0xf, 0xf, true);
  return x + __builtin_bit_cast(float, s);
}

// Full-wave (64) sum via DPP; result broadcast to all lanes via readlane 63.
__device__ __forceinline__ float wave_sum_bcast(float x) {
  float a = x;
  int s = __builtin_bit_cast(int, a);
  s = __builtin_amdgcn_update_dpp(0, s, 0x111, 0xf, 0xf, true);  // row_shr:1
  a += __builtin_bit_cast(float, s);
  s = __builtin_bit_cast(int, a);
  s = __builtin_amdgcn_update_dpp(0, s, 0x112, 0xf, 0xf, true);  // row_shr:2
  a += __builtin_bit_cast(float, s);
  s = __builtin_bit_cast(int, a);
  s = __builtin_amdgcn_update_dpp(0, s, 0x114, 0xf, 0xf, true);  // row_shr:4
  a += __builtin_bit_cast(float, s);
  s = __builtin_bit_cast(int, a);
  s = __builtin_amdgcn_update_dpp(0, s, 0x118, 0xf, 0xf, true);  // row_shr:8
  a += __builtin_bit_cast(float, s);
  s = __builtin_bit_cast(int, a);
  s = __builtin_amdgcn_update_dpp(0, s, 0x142, 0xf, 0xf, true);  // row_bcast:15
  a += __builtin_bit_cast(float, s);
  s = __builtin_bit_cast(int, a);
  s = __builtin_amdgcn_update_dpp(0, s, 0x143, 0xf, 0xf, true);  // row_bcast:31
  a += __builtin_bit_cast(float, s);
  s = __builtin_bit_cast(int, a);
  return __builtin_bit_cast(float, __builtin_amdgcn_readlane(s, 63));
}

// ---------------------------------------------------------------------------
// K1: blocks [0,64):  GRU per batch. 256 threads = (d, p) pairs: thread pair
//                     splits K; per-thread weights w[3][32] (96 VGPRs -> no
//                     spill). DPP pair-sum per gate; one barrier/step.
//                     h history in LDS (f16); bulk dump at end.
//     blocks [64,128): C2 value scan per batch, single wave, DPP reduce.
// ---------------------------------------------------------------------------
__global__ __launch_bounds__(256, 1) void k1_gru_scan(
    const int* __restrict__ c2_seq, const int* __restrict__ d_seq,
    const int* __restrict__ r_seq, const float* __restrict__ D_emb,
    const float* __restrict__ v_d, const float* __restrict__ v_c2,
    const float* __restrict__ R_emb,
    const float* __restrict__ W_ih, const float* __restrict__ W_hh,
    const float* __restrict__ b_ih, const float* __restrict__ b_hh,
    const float* __restrict__ W3, const float* __restrict__ b3,
    const float* __restrict__ W4, const float* __restrict__ b4,
    float* __restrict__ out_h, float* __restrict__ vals_ws)
{
  __shared__ __align__(16) char smem[(S_ + 1) * DV_ * 2 + 2 * S_ * 4];
  const int tid = threadIdx.x;

  if (blockIdx.x < B_) {
    // ------------------ GRU for batch b ------------------
    const int b = blockIdx.x;
    _Float16* hist = reinterpret_cast<_Float16*>(smem);          // (S_+1)*DV_
    float* gl = reinterpret_cast<float*>(smem + (S_ + 1) * DV_ * 2);
    int* rl = reinterpret_cast<int*>(gl + S_);

    for (int i = tid; i < S_; i += 256) {
      gl[i] = D_emb[d_seq[b * S_ + i]];
      rl[i] = r_seq[b * S_ + i];
    }
    const int d = tid >> 1;   // output dim 0..127
    const int p = tid & 1;    // K-half (adjacent lanes -> DPP quad_perm)
    // W_hh rows {d, d+128, d+256}, K-half p, packed f16 pairs: 3 x 32 dwords
    h2v w[3][32];
#pragma unroll
    for (int g = 0; g < 3; ++g) {
      const float4* wr = reinterpret_cast<const float4*>(
          W_hh + (size_t)(d + g * DV_) * DV_ + p * 64);
#pragma unroll
      for (int k = 0; k < 16; ++k) {
        float4 t4 = wr[k];
        h2v lo, hi;
        lo.x = (_Float16)t4.x; lo.y = (_Float16)t4.y;
        hi.x = (_Float16)t4.z; hi.y = (_Float16)t4.w;
        w[g][2 * k] = lo; w[g][2 * k + 1] = hi;
      }
    }
    // collapsed input projections per gate row (redundant across the pair)
    float u[3], p0[3], p1[3], bh[3];
#pragma unroll
    for (int g = 0; g < 3; ++g) {
      const int row = d + g * DV_;
      const float4* wi =
          reinterpret_cast<const float4*>(W_ih + (size_t)row * 2 * DV_);
      const float4* vd4 = reinterpret_cast<const float4*>(v_d);
      const float4* re4 = reinterpret_cast<const float4*>(R_emb);
      float uu = 0.f, pp0 = 0.f, pp1 = 0.f;
#pragma unroll 8
      for (int k = 0; k < DV_ / 4; ++k) {
        float4 a = wi[k], vv = vd4[k];
        uu += a.x * vv.x + a.y * vv.y + a.z * vv.z + a.w * vv.w;
        float4 c = wi[DV_ / 4 + k];
        float4 r0 = re4[k], r1 = re4[DV_ / 4 + k];
        pp0 += c.x * r0.x + c.y * r0.y + c.z * r0.z + c.w * r0.w;
        pp1 += c.x * r1.x + c.y * r1.y + c.z * r1.z + c.w * r1.w;
      }
      const float bi = b_ih[row];
      u[g] = uu; p0[g] = pp0 + bi; p1[g] = pp1 + bi;
      bh[g] = b_hh[row];
    }
    float hreg = 0.f;
    if (tid < DV_) hist[tid] = (_Float16)0.f;
    lds_sync();

    float gv = gl[0];
    int rv = rl[0];
    for (int t = 0; t < S_; ++t) {
      const float xr = gv * u[0] + (rv ? p1[0] : p0[0]);
      const float xz = gv * u[1] + (rv ? p1[1] : p0[1]);
      const float xn = gv * u[2] + (rv ? p1[2] : p0[2]);
      const float4* hb = reinterpret_cast<const float4*>(hist + t * DV_);
      // 4 independent chains per gate, depth 8. Half-row = 64 f16 = 8 float4.
      float a0[4] = {0.f, 0.f, 0.f, 0.f};
      float a1[4] = {0.f, 0.f, 0.f, 0.f};
      float a2[4] = {0.f, 0.f, 0.f, 0.f};
#pragma unroll
      for (int k = 0; k < 8; ++k) {
        float4 hv = hb[p * 8 + k];  // 2 addrs/wave -> 2-way, free
        h2v h0 = __builtin_bit_cast(h2v, hv.x);
        h2v h1 = __builtin_bit_cast(h2v, hv.y);
        h2v h2 = __builtin_bit_cast(h2v, hv.z);
        h2v h3 = __builtin_bit_cast(h2v, hv.w);
        a0[0] = dot2acc(w[0][4 * k + 0], h0, a0[0]);
        a1[0] = dot2acc(w[1][4 * k + 0], h0, a1[0]);
        a2[0] = dot2acc(w[2][4 * k + 0], h0, a2[0]);
        a0[1] = dot2acc(w[0][4 * k + 1], h1, a0[1]);
        a1[1] = dot2acc(w[1][4 * k + 1], h1, a1[1]);
        a2[1] = dot2acc(w[2][4 * k + 1], h1, a2[1]);
        a0[2] = dot2acc(w[0][4 * k + 2], h2, a0[2]);
        a1[2] = dot2acc(w[1][4 * k + 2], h2, a1[2]);
        a2[2] = dot2acc(w[2][4 * k + 2], h2, a2[2]);
        a0[3] = dot2acc(w[0][4 * k + 3], h3, a0[3]);
        a1[3] = dot2acc(w[1][4 * k + 3], h3, a1[3]);
        a2[3] = dot2acc(w[2][4 * k + 3], h3, a2[3]);
      }
      float s0 = (a0[0] + a0[1]) + (a0[2] + a0[3]);
      float s1 = (a1[0] + a1[1]) + (a1[2] + a1[3]);
      float s2 = (a2[0] + a2[1]) + (a2[2] + a2[3]);
      s0 = pair_sum(s0);
      s1 = pair_sum(s1);
      s2 = pair_sum(s2);
      const float r = 1.f / (1.f + __expf(-(xr + s0 + bh[0])));
      const float z = 1.f / (1.f + __expf(-(xz + s1 + bh[1])));
      const float nx = xn + r * (s2 + bh[2]);
      const float e2 = __expf(2.f * nx);
      const float n = (e2 - 1.f) / (e2 + 1.f);
      const float hnew = (1.f - z) * n + z * hreg;
      hreg = hnew;
      if (p == 0) hist[(t + 1) * DV_ + d] = (_Float16)hnew;
      if (t + 1 < S_) {            // prefetch next scalars before barrier
        gv = gl[t + 1];
        rv = rl[t + 1];
      }
      lds_sync();
    }

    // ---------- bulk dump h history (f16 -> f32) ----------
    const uint2* hu2 = reinterpret_cast<const uint2*>(hist + DV_);  // skip row0
    float4* op4 = reinterpret_cast<float4*>(out_h + (size_t)b * S_ * DV_);
    for (int i = tid; i < S_ * DV_ / 4; i += 256) {
      uint2 uu = hu2[i];
      h2v lo = __builtin_bit_cast(h2v, uu.x);
      h2v hi = __builtin_bit_cast(h2v, uu.y);
      float4 f;
      f.x = (float)lo.x; f.y = (float)lo.y;
      f.z = (float)hi.x; f.w = (float)hi.y;
      op4[i] = f;
    }
  } else {
    // ------------------ C2 value scan, single wave, DPP reduce ----------
    const int b = blockIdx.x - B_;
    float* C2s = reinterpret_cast<float*>(smem);                 // NC2_
    float* gl = C2s + NC2_;
    int* rl = reinterpret_cast<int*>(gl + S_);
    int* jl = rl + S_;
    for (int i = tid; i < NC2_; i += 256) C2s[i] = 0.f;
    for (int i = tid; i < S_; i += 256) {
      gl[i] = D_emb[d_seq[b * S_ + i]];
      rl[i] = r_seq[b * S_ + i];
      jl[i] = c2_seq[b * S_ + i];
    }
    __syncthreads();
    if (tid >= 64) return;
    const int lane = tid;
    float a3L = 0, u3L = 0, q0L = 0, q1L = 0;
    float a3H = 0, u3H = 0, q0H = 0, q1H = 0;
    {
      const float4* vc4 = reinterpret_cast<const float4*>(v_c2);
      const float4* vd4 = reinterpret_cast<const float4*>(v_d);
      const float4* re4 = reinterpret_cast<const float4*>(R_emb);
      const float4* wL = reinterpret_cast<const float4*>(W3 + (size_t)lane * 3 * DV_);
      const float4* wH = reinterpret_cast<const float4*>(W3 + (size_t)(lane + 64) * 3 * DV_);
#pragma unroll 8
      for (int k = 0; k < DV_ / 4; ++k) {
        float4 cc = vc4[k], dd = vd4[k];
        float4 r0 = re4[k], r1 = re4[DV_ / 4 + k];
        float4 aL = wL[k], aH = wH[k];
        a3L += aL.x * cc.x + aL.y * cc.y + aL.z * cc.z + aL.w * cc.w;
        a3H += aH.x * cc.x + aH.y * cc.y + aH.z * cc.z + aH.w * cc.w;
        float4 bL = wL[DV_ / 4 + k], bH = wH[DV_ / 4 + k];
        u3L += bL.x * dd.x + bL.y * dd.y + bL.z * dd.z + bL.w * dd.w;
        u3H += bH.x * dd.x + bH.y * dd.y + bH.z * dd.z + bH.w * dd.w;
        float4 cL = wL[2 * (DV_ / 4) + k], cH = wH[2 * (DV_ / 4) + k];
        q0L += cL.x * r0.x + cL.y * r0.y + cL.z * r0.z + cL.w * r0.w;
        q1L += cL.x * r1.x + cL.y * r1.y + cL.z * r1.z + cL.w * r1.w;
        q0H += cH.x * r0.x + cH.y * r0.y + cH.z * r0.z + cH.w * r0.w;
        q1H += cH.x * r1.x + cH.y * r1.y + cH.z * r1.z + cH.w * r1.w;
      }
      float bbL = b3[lane], bbH = b3[lane + 64];
      q0L += bbL; q1L += bbL; q0H += bbH; q1H += bbH;
    }
    const float w4L = W4[lane], w4H = W4[lane + 64];
    const float b4v = b4[0];

    int jc = jl[0];
    float gv = gl[0];
    int rv = rl[0];
    float pf = 0.f;
    float lastv = 0.f;
    int lastj = -1;
    for (int t = 0; t < S_; ++t) {
      const int tn = (t + 1 < S_) ? t + 1 : 0;
      const int jn = jl[tn];
      const float gvn = gl[tn];
      const int rvn = rl[tn];
      const float pfn = C2s[jn];   // prefetch; patched via lastj/lastv
      const float beta = (jc == lastj) ? lastv : pf;
      float hL = beta * a3L + gv * u3L + (rv ? q1L : q0L);
      float hH = beta * a3H + gv * u3H + (rv ? q1H : q0H);
      const float part = fmaxf(hL, 0.f) * w4L + fmaxf(hH, 0.f) * w4H;
      const float val = wave_sum_bcast(part) + b4v;
      if (lane == 0) {
        C2s[jc] = val;
        vals_ws[b * S_ + t] = val;
      }
      lastj = jc; lastv = val;
      jc = jn; gv = gvn; rv = rvn; pf = pfn;
    }
  }
}

// ---------------------------------------------------------------------------
// K2: blocks [0,256):    alpha MLP, (b, 50-row chunk)
//     blocks [256,1856): C2_seq fill, (b, 8-row chunk), barrier-free rows
// ---------------------------------------------------------------------------
__global__ __launch_bounds__(256) void k2_alpha_fill(
    const int* __restrict__ c2_seq,
    const float* __restrict__ W1, const float* __restrict__ b1,
    const float* __restrict__ W2, const float* __restrict__ b2,
    const float* __restrict__ vals_ws, const float* __restrict__ h_seq,
    float* __restrict__ out_alpha, float* __restrict__ out_c2)
{
  const int tid = threadIdx.x;
  if (blockIdx.x < NACH * B_) {
    // ------------------ alpha ------------------
    const int b = blockIdx.x >> 2, c = blockIdx.x & 3;
    const int sbeg = c * ACH, send = sbeg + ACH;
    __shared__ float4 hb4[2][DV_ / 4];
    __shared__ float red[4];
    const int grp = tid >> 7, d = tid & 127;
    float w1r[DV_];
    {
      const float4* wr = reinterpret_cast<const float4*>(W1 + (size_t)d * DV_);
#pragma unroll
      for (int k = 0; k < DV_ / 4; ++k) {
        float4 t4 = wr[k];
        w1r[4 * k] = t4.x; w1r[4 * k + 1] = t4.y;
        w1r[4 * k + 2] = t4.z; w1r[4 * k + 3] = t4.w;
      }
    }
    const float b1v = b1[d], w2v = W2[d], b2v = b2[0];
    float* hb = reinterpret_cast<float*>(hb4[grp]);
    for (int s = sbeg; s < send; s += 2) {
      const int ss = s + grp;
      hb[d] = h_seq[((size_t)(b * S_ + ss)) * DV_ + d];
      __syncthreads();
      float y0 = b1v, y1 = 0, y2 = 0, y3 = 0;
#pragma unroll
      for (int k = 0; k < DV_ / 4; ++k) {
        float4 hv = hb4[grp][k];
        y0 += w1r[4 * k + 0] * hv.x; y1 += w1r[4 * k + 1] * hv.y;
        y2 += w1r[4 * k + 2] * hv.z; y3 += w1r[4 * k + 3] * hv.w;
      }
      float part = w2v * fmaxf((y0 + y1) + (y2 + y3), 0.f);
#pragma unroll
      for (int off = 1; off < 64; off <<= 1) part += __shfl_xor(part, off);
      if ((tid & 63) == 0) red[tid >> 6] = part;
      __syncthreads();
      if (d == 0) out_alpha[b * S_ + ss] = red[2 * grp] + red[2 * grp + 1] + b2v;
      __syncthreads();
    }
  } else {
    // ------------------ C2_seq fill ------------------
    const int blk = blockIdx.x - NACH * B_;
    const int b = blk / NFCH, c = blk % NFCH;
    const int s0 = c * FCH;
    __shared__ float vls[S_];
    __shared__ int jl[S_];
    for (int i = tid; i < S_; i += 256) {
      vls[i] = vals_ws[b * S_ + i];
      jl[i] = c2_seq[b * S_ + i];
    }
    __syncthreads();
    // thread owns 16 columns: float4 indices f = tid + jj*256
    f4v v0 = {0.f, 0.f, 0.f, 0.f}, v1 = v0, v2 = v0, v3 = v0;

#define APPLY_EVT(T)                                                          \
    {                                                                         \
      const int j_ = jl[(T)];                                                 \
      const int f_ = j_ >> 2;                                                 \
      if ((f_ & 255) == tid) {                                                \
        const float vv_ = vls[(T)];                                           \
        const int rr_ = f_ >> 8, q_ = j_ & 3;                                 \
        if (rr_ == 0) {                                                       \
          if (q_ == 0) v0.x = vv_; else if (q_ == 1) v0.y = vv_;              \
          else if (q_ == 2) v0.z = vv_; else v0.w = vv_;                      \
        } else if (rr_ == 1) {                                                \
          if (q_ == 0) v1.x = vv_; else if (q_ == 1) v1.y = vv_;              \
          else if (q_ == 2) v1.z = vv_; else v1.w = vv_;                      \
        } else if (rr_ == 2) {                                                \
          if (q_ == 0) v2.x = vv_; else if (q_ == 1) v2.y = vv_;              \
          else if (q_ == 2) v2.z = vv_; else v2.w = vv_;                      \
        } else {                                                              \
          if (q_ == 0) v3.x = vv_; else if (q_ == 1) v3.y = vv_;              \
          else if (q_ == 2) v3.z = vv_; else v3.w = vv_;                      \
        }                                                                     \
      }                                                                       \
    }

    for (int t = 0; t < s0; ++t) APPLY_EVT(t);

    f4v* dst4 = reinterpret_cast<f4v*>(out_c2 + (size_t)b * S_ * NC2_);
    for (int s = s0; s < s0 + FCH; ++s) {
      APPLY_EVT(s);
      f4v* drow = dst4 + (size_t)s * (NC2_ / 4);
      __builtin_nontemporal_store(v0, drow + tid);
      __builtin_nontemporal_store(v1, drow + tid + 256);
      __builtin_nontemporal_store(v2, drow + tid + 512);
      __builtin_nontemporal_store(v3, drow + tid + 768);
    }
#undef APPLY_EVT
  }
}

extern "C" void kernel_launch(void* const* d_in, const int* in_sizes, int n_in,
                              void* d_out, int out_size, void* d_ws, size_t ws_size,
                              hipStream_t stream) {
  const int* c2_seq = (const int*)d_in[1];
  const int* d_seq = (const int*)d_in[3];
  const int* r_seq = (const int*)d_in[4];
  const float* D_emb = (const float*)d_in[5];
  const float* v_d = (const float*)d_in[6];
  const float* v_c2 = (const float*)d_in[7];
  const float* R_emb = (const float*)d_in[8];
  const float* W_ih = (const float*)d_in[9];
  const float* W_hh = (const float*)d_in[10];
  const float* b_ih = (const float*)d_in[11];
  const float* b_hh = (const float*)d_in[12];
  const float* W1 = (const float*)d_in[13];
  const float* b1 = (const float*)d_in[14];
  const float* W2 = (const float*)d_in[15];
  const float* b2 = (const float*)d_in[16];
  const float* W3 = (const float*)d_in[17];
  const float* b3 = (const float*)d_in[18];
  const float* W4 = (const float*)d_in[19];
  const float* b4 = (const float*)d_in[20];

  float* out = (float*)d_out;
  float* out_alpha = out;                                  // [B,S]
  float* out_h = out + B_ * S_;                            // [B,S,DV]
  float* out_c2 = out + B_ * S_ + (size_t)B_ * S_ * DV_;   // [B,S,NC2]
  float* vals_ws = (float*)d_ws;                           // [B*S] floats

  k1_gru_scan<<<dim3(2 * B_), dim3(256), 0, stream>>>(
      c2_seq, d_seq, r_seq, D_emb, v_d, v_c2, R_emb, W_ih, W_hh, b_ih, b_hh,
      W3, b3, W4, b4, out_h, vals_ws);
  k2_alpha_fill<<<dim3(NACH * B_ + B_ * NFCH), dim3(256), 0, stream>>>(
      c2_seq, W1, b1, W2, b2, vals_ws, out_h, out_alpha, out_c2);
}

// Round 12
// 177.856 us; speedup vs baseline: 1.8160x; 1.0323x over previous
//
#include <hip/hip_runtime.h>

namespace {
constexpr int B_ = 64, S_ = 200, DV_ = 128, NC2_ = 4096;
constexpr int FCH = 8, NFCH = 25;    // fill: 25 chunks x 8 rows
constexpr int ACH = 50, NACH = 4;    // alpha: 4 chunks x 50 rows
}

typedef float f4v __attribute__((ext_vector_type(4)));
typedef float f32x4 __attribute__((ext_vector_type(4)));
typedef _Float16 half8 __attribute__((ext_vector_type(8)));
typedef _Float16 h2v __attribute__((ext_vector_type(2)));

// LDS-only barrier: no vmcnt drain.
__device__ __forceinline__ void lds_sync() {
  asm volatile("s_waitcnt lgkmcnt(0)\n\ts_barrier" ::: "memory");
}

// Full-wave (64) sum via DPP; result broadcast to all lanes via readlane 63.
__device__ __forceinline__ float wave_sum_bcast(float x) {
  float a = x;
  int s = __builtin_bit_cast(int, a);
  s = __builtin_amdgcn_update_dpp(0, s, 0x111, 0xf, 0xf, true);  // row_shr:1
  a += __builtin_bit_cast(float, s);
  s = __builtin_bit_cast(int, a);
  s = __builtin_amdgcn_update_dpp(0, s, 0x112, 0xf, 0xf, true);  // row_shr:2
  a += __builtin_bit_cast(float, s);
  s = __builtin_bit_cast(int, a);
  s = __builtin_amdgcn_update_dpp(0, s, 0x114, 0xf, 0xf, true);  // row_shr:4
  a += __builtin_bit_cast(float, s);
  s = __builtin_bit_cast(int, a);
  s = __builtin_amdgcn_update_dpp(0, s, 0x118, 0xf, 0xf, true);  // row_shr:8
  a += __builtin_bit_cast(float, s);
  s = __builtin_bit_cast(int, a);
  s = __builtin_amdgcn_update_dpp(0, s, 0x142, 0xf, 0xf, true);  // row_bcast:15
  a += __builtin_bit_cast(float, s);
  s = __builtin_bit_cast(int, a);
  s = __builtin_amdgcn_update_dpp(0, s, 0x143, 0xf, 0xf, true);  // row_bcast:31
  a += __builtin_bit_cast(float, s);
  s = __builtin_bit_cast(int, a);
  return __builtin_bit_cast(float, __builtin_amdgcn_readlane(s, 63));
}

// ---------------------------------------------------------------------------
// K1: blocks [0,64):  GRU per batch via broadcast-MFMA. 8 waves; wave w owns
//                     dims [16w,16w+16) x 3 gates (3 N-tiles x K=128).
//                     A-rows are all h (broadcast LDS read); C col = dim,
//                     so all 3 gates of dim d are lane-local. One barrier
//                     per step; h double-buffered f16[2][128] in LDS.
//     blocks [64,128): C2 value scan per batch, single wave, DPP reduce.
// ---------------------------------------------------------------------------
__global__ __launch_bounds__(512, 1) void k1_gru_scan(
    const int* __restrict__ c2_seq, const int* __restrict__ d_seq,
    const int* __restrict__ r_seq, const float* __restrict__ D_emb,
    const float* __restrict__ v_d, const float* __restrict__ v_c2,
    const float* __restrict__ R_emb,
    const float* __restrict__ W_ih, const float* __restrict__ W_hh,
    const float* __restrict__ b_ih, const float* __restrict__ b_hh,
    const float* __restrict__ W3, const float* __restrict__ b3,
    const float* __restrict__ W4, const float* __restrict__ b4,
    float* __restrict__ out_h, float* __restrict__ vals_ws)
{
  __shared__ __align__(16) char smem[18944];
  const int tid = threadIdx.x;

  if (blockIdx.x < B_) {
    // ------------------ GRU for batch b ------------------
    const int b = blockIdx.x;
    _Float16* hist = reinterpret_cast<_Float16*>(smem);          // [2][128] f16
    float* gl = reinterpret_cast<float*>(smem + 512);            // [200]
    int* rl = reinterpret_cast<int*>(smem + 1312);               // [200]
    float* u_l = reinterpret_cast<float*>(smem + 2112);          // [384]
    float* p0_l = u_l + 384;
    float* p1_l = p0_l + 384;
    float* bh_l = p1_l + 384;

    for (int i = tid; i < S_; i += 512) {
      gl[i] = D_emb[d_seq[b * S_ + i]];
      rl[i] = r_seq[b * S_ + i];
    }
    if (tid < 256) reinterpret_cast<_Float16*>(hist)[tid] = (_Float16)0.f;

    // collapsed input projections per gate row -> LDS
    if (tid < 384) {
      const int row = tid;
      const float4* wi =
          reinterpret_cast<const float4*>(W_ih + (size_t)row * 2 * DV_);
      const float4* vd4 = reinterpret_cast<const float4*>(v_d);
      const float4* re4 = reinterpret_cast<const float4*>(R_emb);
      float uu = 0.f, pp0 = 0.f, pp1 = 0.f;
#pragma unroll 8
      for (int k = 0; k < DV_ / 4; ++k) {
        float4 a = wi[k], vv = vd4[k];
        uu += a.x * vv.x + a.y * vv.y + a.z * vv.z + a.w * vv.w;
        float4 c = wi[DV_ / 4 + k];
        float4 r0 = re4[k], r1 = re4[DV_ / 4 + k];
        pp0 += c.x * r0.x + c.y * r0.y + c.z * r0.z + c.w * r0.w;
        pp1 += c.x * r1.x + c.y * r1.y + c.z * r1.z + c.w * r1.w;
      }
      const float bi = b_ih[row];
      u_l[row] = uu; p0_l[row] = pp0 + bi; p1_l[row] = pp1 + bi;
      bh_l[row] = b_hh[row];
    }

    // B-fragments (W_hh^T), verified layout from R10: lane l holds
    // B[k=(l>>4)*8+j][col=l&15] for gate g, ktile kt.
    const int w = tid >> 6, l = tid & 63;
    const int col = l & 15, kg = l >> 4;
    const int d = 16 * w + col;
    half8 bf[3][4];
#pragma unroll
    for (int g = 0; g < 3; ++g) {
      const float* wr = W_hh + (size_t)(g * DV_ + d) * DV_;
#pragma unroll
      for (int kt = 0; kt < 4; ++kt) {
        const int k0 = kt * 32 + kg * 8;
        const float4 lo = *reinterpret_cast<const float4*>(wr + k0);
        const float4 hi = *reinterpret_cast<const float4*>(wr + k0 + 4);
        half8 hb;
        hb[0] = (_Float16)lo.x; hb[1] = (_Float16)lo.y;
        hb[2] = (_Float16)lo.z; hb[3] = (_Float16)lo.w;
        hb[4] = (_Float16)hi.x; hb[5] = (_Float16)hi.y;
        hb[6] = (_Float16)hi.z; hb[7] = (_Float16)hi.w;
        bf[g][kt] = hb;
      }
    }
    __syncthreads();

    // per-lane scalars for dim d (all 3 gate rows)
    float u3[3], p03[3], p13[3], bh3[3];
#pragma unroll
    for (int g = 0; g < 3; ++g) {
      u3[g] = u_l[g * DV_ + d];
      p03[g] = p0_l[g * DV_ + d];
      p13[g] = p1_l[g * DV_ + d];
      bh3[g] = bh_l[g * DV_ + d];
    }
    float hprev = 0.f;
    float gv = gl[0];
    int rv = rl[0];

    float* outp = out_h + (size_t)b * S_ * DV_ + d;
    for (int t = 0; t < S_; ++t) {
      const int cur = t & 1;
      // A-fragments: every row of A = h (broadcast read; 4 addrs/wave)
      half8 af[4];
#pragma unroll
      for (int kt = 0; kt < 4; ++kt)
        af[kt] = *reinterpret_cast<const half8*>(&hist[cur * DV_ + kt * 32 + kg * 8]);
      f32x4 a0 = {0.f, 0.f, 0.f, 0.f}, a1 = a0, a2 = a0;
#pragma unroll
      for (int kt = 0; kt < 4; ++kt) {
        a0 = __builtin_amdgcn_mfma_f32_16x16x32_f16(af[kt], bf[0][kt], a0, 0, 0, 0);
        a1 = __builtin_amdgcn_mfma_f32_16x16x32_f16(af[kt], bf[1][kt], a1, 0, 0, 0);
        a2 = __builtin_amdgcn_mfma_f32_16x16x32_f16(af[kt], bf[2][kt], a2, 0, 0, 0);
      }
      const float xr = gv * u3[0] + (rv ? p13[0] : p03[0]);
      const float xz = gv * u3[1] + (rv ? p13[1] : p03[1]);
      const float xn = gv * u3[2] + (rv ? p13[2] : p03[2]);
      const float r = 1.f / (1.f + __expf(-(xr + a0[0] + bh3[0])));
      const float z = 1.f / (1.f + __expf(-(xz + a1[0] + bh3[1])));
      const float nx = xn + r * (a2[0] + bh3[2]);
      const float e2 = __expf(2.f * nx);
      const float n = (e2 - 1.f) / (e2 + 1.f);
      const float hnew = (1.f - z) * n + z * hprev;
      hprev = hnew;
      if (kg == 0) {
        outp[(size_t)t * DV_] = hnew;                 // async global store
        hist[(cur ^ 1) * DV_ + d] = (_Float16)hnew;   // next-step h
      }
      if (t + 1 < S_) { gv = gl[t + 1]; rv = rl[t + 1]; }
      lds_sync();
    }
  } else {
    // ------------------ C2 value scan, single wave, DPP reduce ----------
    const int b = blockIdx.x - B_;
    float* C2s = reinterpret_cast<float*>(smem);                 // 4096
    float* gl = reinterpret_cast<float*>(smem + 16384);          // [200]
    int* rl = reinterpret_cast<int*>(smem + 17184);
    int* jl = reinterpret_cast<int*>(smem + 17984);
    for (int i = tid; i < NC2_; i += 512) C2s[i] = 0.f;
    for (int i = tid; i < S_; i += 512) {
      gl[i] = D_emb[d_seq[b * S_ + i]];
      rl[i] = r_seq[b * S_ + i];
      jl[i] = c2_seq[b * S_ + i];
    }
    __syncthreads();
    if (tid >= 64) return;
    const int lane = tid;
    float a3L = 0, u3L = 0, q0L = 0, q1L = 0;
    float a3H = 0, u3H = 0, q0H = 0, q1H = 0;
    {
      const float4* vc4 = reinterpret_cast<const float4*>(v_c2);
      const float4* vd4 = reinterpret_cast<const float4*>(v_d);
      const float4* re4 = reinterpret_cast<const float4*>(R_emb);
      const float4* wL = reinterpret_cast<const float4*>(W3 + (size_t)lane * 3 * DV_);
      const float4* wH = reinterpret_cast<const float4*>(W3 + (size_t)(lane + 64) * 3 * DV_);
#pragma unroll 8
      for (int k = 0; k < DV_ / 4; ++k) {
        float4 cc = vc4[k], dd = vd4[k];
        float4 r0 = re4[k], r1 = re4[DV_ / 4 + k];
        float4 aL = wL[k], aH = wH[k];
        a3L += aL.x * cc.x + aL.y * cc.y + aL.z * cc.z + aL.w * cc.w;
        a3H += aH.x * cc.x + aH.y * cc.y + aH.z * cc.z + aH.w * cc.w;
        float4 bL = wL[DV_ / 4 + k], bH = wH[DV_ / 4 + k];
        u3L += bL.x * dd.x + bL.y * dd.y + bL.z * dd.z + bL.w * dd.w;
        u3H += bH.x * dd.x + bH.y * dd.y + bH.z * dd.z + bH.w * dd.w;
        float4 cL = wL[2 * (DV_ / 4) + k], cH = wH[2 * (DV_ / 4) + k];
        q0L += cL.x * r0.x + cL.y * r0.y + cL.z * r0.z + cL.w * r0.w;
        q1L += cL.x * r1.x + cL.y * r1.y + cL.z * r1.z + cL.w * r1.w;
        q0H += cH.x * r0.x + cH.y * r0.y + cH.z * r0.z + cH.w * r0.w;
        q1H += cH.x * r1.x + cH.y * r1.y + cH.z * r1.z + cH.w * r1.w;
      }
      float bbL = b3[lane], bbH = b3[lane + 64];
      q0L += bbL; q1L += bbL; q0H += bbH; q1H += bbH;
    }
    const float w4L = W4[lane], w4H = W4[lane + 64];
    const float b4v = b4[0];

    int jc = jl[0];
    float gv = gl[0];
    int rv = rl[0];
    float pf = 0.f;
    float lastv = 0.f;
    int lastj = -1;
    for (int t = 0; t < S_; ++t) {
      const int tn = (t + 1 < S_) ? t + 1 : 0;
      const int jn = jl[tn];
      const float gvn = gl[tn];
      const int rvn = rl[tn];
      const float pfn = C2s[jn];   // prefetch; patched via lastj/lastv
      const float beta = (jc == lastj) ? lastv : pf;
      float hL = beta * a3L + gv * u3L + (rv ? q1L : q0L);
      float hH = beta * a3H + gv * u3H + (rv ? q1H : q0H);
      const float part = fmaxf(hL, 0.f) * w4L + fmaxf(hH, 0.f) * w4H;
      const float val = wave_sum_bcast(part) + b4v;
      if (lane == 0) {
        C2s[jc] = val;
        vals_ws[b * S_ + t] = val;
      }
      lastj = jc; lastv = val;
      jc = jn; gv = gvn; rv = rvn; pf = pfn;
    }
  }
}

// ---------------------------------------------------------------------------
// K2: blocks [0,256):    alpha MLP, (b, 50-row chunk)
//     blocks [256,1856): C2_seq fill, (b, 8-row chunk), barrier-free rows
// ---------------------------------------------------------------------------
__global__ __launch_bounds__(256) void k2_alpha_fill(
    const int* __restrict__ c2_seq,
    const float* __restrict__ W1, const float* __restrict__ b1,
    const float* __restrict__ W2, const float* __restrict__ b2,
    const float* __restrict__ vals_ws, const float* __restrict__ h_seq,
    float* __restrict__ out_alpha, float* __restrict__ out_c2)
{
  const int tid = threadIdx.x;
  if (blockIdx.x < NACH * B_) {
    // ------------------ alpha ------------------
    const int b = blockIdx.x >> 2, c = blockIdx.x & 3;
    const int sbeg = c * ACH, send = sbeg + ACH;
    __shared__ float4 hb4[2][DV_ / 4];
    __shared__ float red[4];
    const int grp = tid >> 7, d = tid & 127;
    float w1r[DV_];
    {
      const float4* wr = reinterpret_cast<const float4*>(W1 + (size_t)d * DV_);
#pragma unroll
      for (int k = 0; k < DV_ / 4; ++k) {
        float4 t4 = wr[k];
        w1r[4 * k] = t4.x; w1r[4 * k + 1] = t4.y;
        w1r[4 * k + 2] = t4.z; w1r[4 * k + 3] = t4.w;
      }
    }
    const float b1v = b1[d], w2v = W2[d], b2v = b2[0];
    float* hb = reinterpret_cast<float*>(hb4[grp]);
    for (int s = sbeg; s < send; s += 2) {
      const int ss = s + grp;
      hb[d] = h_seq[((size_t)(b * S_ + ss)) * DV_ + d];
      __syncthreads();
      float y0 = b1v, y1 = 0, y2 = 0, y3 = 0;
#pragma unroll
      for (int k = 0; k < DV_ / 4; ++k) {
        float4 hv = hb4[grp][k];
        y0 += w1r[4 * k + 0] * hv.x; y1 += w1r[4 * k + 1] * hv.y;
        y2 += w1r[4 * k + 2] * hv.z; y3 += w1r[4 * k + 3] * hv.w;
      }
      float part = w2v * fmaxf((y0 + y1) + (y2 + y3), 0.f);
#pragma unroll
      for (int off = 1; off < 64; off <<= 1) part += __shfl_xor(part, off);
      if ((tid & 63) == 0) red[tid >> 6] = part;
      __syncthreads();
      if (d == 0) out_alpha[b * S_ + ss] = red[2 * grp] + red[2 * grp + 1] + b2v;
      __syncthreads();
    }
  } else {
    // ------------------ C2_seq fill ------------------
    const int blk = blockIdx.x - NACH * B_;
    const int b = blk / NFCH, c = blk % NFCH;
    const int s0 = c * FCH;
    __shared__ float vls[S_];
    __shared__ int jl[S_];
    for (int i = tid; i < S_; i += 256) {
      vls[i] = vals_ws[b * S_ + i];
      jl[i] = c2_seq[b * S_ + i];
    }
    __syncthreads();
    // thread owns 16 columns: float4 indices f = tid + jj*256
    f4v v0 = {0.f, 0.f, 0.f, 0.f}, v1 = v0, v2 = v0, v3 = v0;

#define APPLY_EVT(T)                                                          \
    {                                                                         \
      const int j_ = jl[(T)];                                                 \
      const int f_ = j_ >> 2;                                                 \
      if ((f_ & 255) == tid) {                                                \
        const float vv_ = vls[(T)];                                           \
        const int rr_ = f_ >> 8, q_ = j_ & 3;                                 \
        if (rr_ == 0) {                                                       \
          if (q_ == 0) v0.x = vv_; else if (q_ == 1) v0.y = vv_;              \
          else if (q_ == 2) v0.z = vv_; else v0.w = vv_;                      \
        } else if (rr_ == 1) {                                                \
          if (q_ == 0) v1.x = vv_; else if (q_ == 1) v1.y = vv_;              \
          else if (q_ == 2) v1.z = vv_; else v1.w = vv_;                      \
        } else if (rr_ == 2) {                                                \
          if (q_ == 0) v2.x = vv_; else if (q_ == 1) v2.y = vv_;              \
          else if (q_ == 2) v2.z = vv_; else v2.w = vv_;                      \
        } else {                                                              \
          if (q_ == 0) v3.x = vv_; else if (q_ == 1) v3.y = vv_;              \
          else if (q_ == 2) v3.z = vv_; else v3.w = vv_;                      \
        }                                                                     \
      }                                                                       \
    }

    for (int t = 0; t < s0; ++t) APPLY_EVT(t);

    f4v* dst4 = reinterpret_cast<f4v*>(out_c2 + (size_t)b * S_ * NC2_);
    for (int s = s0; s < s0 + FCH; ++s) {
      APPLY_EVT(s);
      f4v* drow = dst4 + (size_t)s * (NC2_ / 4);
      __builtin_nontemporal_store(v0, drow + tid);
      __builtin_nontemporal_store(v1, drow + tid + 256);
      __builtin_nontemporal_store(v2, drow + tid + 512);
      __builtin_nontemporal_store(v3, drow + tid + 768);
    }
#undef APPLY_EVT
  }
}

extern "C" void kernel_launch(void* const* d_in, const int* in_sizes, int n_in,
                              void* d_out, int out_size, void* d_ws, size_t ws_size,
                              hipStream_t stream) {
  const int* c2_seq = (const int*)d_in[1];
  const int* d_seq = (const int*)d_in[3];
  const int* r_seq = (const int*)d_in[4];
  const float* D_emb = (const float*)d_in[5];
  const float* v_d = (const float*)d_in[6];
  const float* v_c2 = (const float*)d_in[7];
  const float* R_emb = (const float*)d_in[8];
  const float* W_ih = (const float*)d_in[9];
  const float* W_hh = (const float*)d_in[10];
  const float* b_ih = (const float*)d_in[11];
  const float* b_hh = (const float*)d_in[12];
  const float* W1 = (const float*)d_in[13];
  const float* b1 = (const float*)d_in[14];
  const float* W2 = (const float*)d_in[15];
  const float* b2 = (const float*)d_in[16];
  const float* W3 = (const float*)d_in[17];
  const float* b3 = (const float*)d_in[18];
  const float* W4 = (const float*)d_in[19];
  const float* b4 = (const float*)d_in[20];

  float* out = (float*)d_out;
  float* out_alpha = out;                                  // [B,S]
  float* out_h = out + B_ * S_;                            // [B,S,DV]
  float* out_c2 = out + B_ * S_ + (size_t)B_ * S_ * DV_;   // [B,S,NC2]
  float* vals_ws = (float*)d_ws;                           // [B*S] floats

  k1_gru_scan<<<dim3(2 * B_), dim3(512), 0, stream>>>(
      c2_seq, d_seq, r_seq, D_emb, v_d, v_c2, R_emb, W_ih, W_hh, b_ih, b_hh,
      W3, b3, W4, b4, out_h, vals_ws);
  k2_alpha_fill<<<dim3(NACH * B_ + B_ * NFCH), dim3(256), 0, stream>>>(
      c2_seq, W1, b1, W2, b2, vals_ws, out_h, out_alpha, out_c2);
}